// Round 1
// 104.436 us; speedup vs baseline: 1.1424x; 1.1424x over previous
//
#include <hip/hip_runtime.h>
#include <stdint.h>

#define NH 32   // heads (fixed by table shapes)

__device__ __forceinline__ float bf_to_f(uint16_t u)
{
    return __uint_as_float(((uint32_t)u) << 16);
}

// Async global->LDS 16B copy. LDS dest is wave-uniform base + lane*16, so the
// LDS layout must be linear in lane order (it is: we pre-swizzle T in prep and
// keep both sides of the copy linear — guide rule #21).
__device__ __forceinline__ void cp16(const void* g, void* l)
{
    __builtin_amdgcn_global_load_lds(
        (const __attribute__((address_space(1))) void*)g,
        (__attribute__((address_space(3))) void*)l, 16, 0, 0);
}

// Block-wide dtype sniff on first 4096 B of spd_table. bf16 N(0,1) never has
// exp field >= 0x89; fp32 low halves do with prob ~1. Returns 1 if fp32.
__device__ __forceinline__ int block_detect_fp32(const uint16_t* p16, int tid,
                                                 int* s_flag)
{
    if (tid == 0) *s_flag = 0;
    __syncthreads();
    const ushort4* p = (const ushort4*)p16;
    ushort4 a = p[tid * 2];
    ushort4 b = p[tid * 2 + 1];
    int big = 0;
    big |= (((a.x >> 7) & 0xFF) >= 0x89); big |= (((a.y >> 7) & 0xFF) >= 0x89);
    big |= (((a.z >> 7) & 0xFF) >= 0x89); big |= (((a.w >> 7) & 0xFF) >= 0x89);
    big |= (((b.x >> 7) & 0xFF) >= 0x89); big |= (((b.y >> 7) & 0xFF) >= 0x89);
    big |= (((b.z >> 7) & 0xFF) >= 0x89); big |= (((b.w >> 7) & 0xFF) >= 0x89);
    if (big) atomicOr(s_flag, 1);
    __syncthreads();
    return *s_flag;
}

// ---------------------------------------------------------------------------
// Fused prep:
//  threads [0, totalT)           : T[d][e][k] = sum_h etab[e][h]*W[d,h,k],
//                                  stored PRE-SWIZZLED (float4 group m of row e
//                                  lands at group m^(e&7)) so bond2d can stage
//                                  with linear global_load_lds and read with
//                                  the XOR-swizzled address (conflict-limited
//                                  to ~2x, m136).
//  threads [totalT, totalT+spd_n): spdT[h][s] = spd[s][h] in fp32 (TRANSPOSED
//                                  so a random-s gather at fixed h spreads
//                                  banks by s%32 instead of all-same-bank).
// ---------------------------------------------------------------------------
__global__ __launch_bounds__(256) void prep(
    const void* __restrict__ edge_table,
    const void* __restrict__ W,
    const void* __restrict__ spd,
    float* __restrict__ T,
    float* __restrict__ spdT,
    int totalT, int spd_n)
{
    __shared__ int s_flag;
    const int tid = threadIdx.x;
    const int is_fp32 = block_detect_fp32((const uint16_t*)spd, tid, &s_flag);
    int g = blockIdx.x * 256 + tid;
    if (g < totalT) {
        int d = g >> 10, e = (g >> 5) & 31, k = g & 31;
        float acc = 0.f;
        if (is_fp32) {
            const float* et = (const float*)edge_table + e * NH;
            const float* w  = (const float*)W + d * NH * NH + k;
#pragma unroll
            for (int h = 0; h < NH; ++h) acc += et[h] * w[h * NH];
        } else {
            const uint16_t* et = (const uint16_t*)edge_table + e * NH;
            const uint16_t* w  = (const uint16_t*)W + d * NH * NH + k;
#pragma unroll
            for (int h = 0; h < NH; ++h) acc += bf_to_f(et[h]) * bf_to_f(w[h * NH]);
        }
        int k4 = (k >> 2) ^ (e & 7);                       // XOR bank swizzle
        T[(d << 10) | (e << 5) | (k4 << 2) | (k & 3)] = acc;
    } else {
        int i = g - totalT;
        if (i < spd_n) {
            float v = is_fp32 ? ((const float*)spd)[i]
                              : bf_to_f(((const uint16_t*)spd)[i]);
            int s = i >> 5, h = i & 31;                    // input [s][h]
            spdT[h * (spd_n >> 5) + s] = v;                // output [h][s]
        }
    }
}

// ---------------------------------------------------------------------------
// Main kernel (R8 structure).
// 1 pair/thread, 1024 blocks, T-LDS chunked to 8 d-rows (32 KiB) + spdT table
// (8 KiB) = 40 KiB/block -> 4 blocks/CU (163840 B = exactly the 160 KiB LDS),
// 16 waves/CU vs R5's 8: doubles latency hiding for the LDS gather / store
// drain. Staging via global_load_lds of the pre-swizzled T (linear both
// sides). phi_spd gather moved off the L1-split global path onto the
// transposed LDS table (bank = s%32, ~2-way for random s -> near-free).
// ---------------------------------------------------------------------------
__global__ __launch_bounds__(256, 4) void bond2d(
    const int* __restrict__ spatial,
    const int* __restrict__ edge,
    const float4* __restrict__ SgT,      // spdT as float4, NH*ns floats
    const float4* __restrict__ Tg,       // pre-swizzled T
    float* __restrict__ out,
    int npairs, int D, int ns)
{
    __shared__ float4 Tl[2048];          // 32 KiB: 8 d-rows x 256 float4
    __shared__ float4 Sl4[512];          // 8 KiB : spdT [NH][ns]
    float* Sl = (float*)Sl4;

    const int t  = threadIdx.x;
    const int p0 = blockIdx.x * 256 + t;
    const bool valid = (p0 < npairs);
    const int p  = valid ? p0 : 0;

    const int s_val = spatial[p];

    // stage spdT once (512 float4 / 256 threads = 2 cp16/thread)
    const int nsf4 = (NH * ns) >> 2;
    for (int i = t; i < nsf4; i += 256)
        cp16(SgT + i, Sl4 + i);

    float acc[32];
#pragma unroll
    for (int k = 0; k < 32; ++k) acc[k] = 0.f;

    const int* erow = edge + (size_t)p * D;

    for (int c0 = 0; c0 < D; c0 += 8) {
        const int dlen = (D - c0 < 8) ? (D - c0) : 8;
        if (c0) __syncthreads();          // prior chunk's reads complete
        if (dlen == 8) {
#pragma unroll
            for (int i = 0; i < 8; ++i)
                cp16(Tg + (c0 + i) * 256 + t, Tl + i * 256 + t);
            int4 q0 = *(const int4*)(erow + c0);
            int4 q1 = *(const int4*)(erow + c0 + 4);
            __syncthreads();              // cp16s drained (vmcnt0 at barrier)
            int ev[8] = {q0.x, q0.y, q0.z, q0.w, q1.x, q1.y, q1.z, q1.w};
#pragma unroll
            for (int d = 0; d < 8; ++d) {
                int e = ev[d];
                int boff = (d << 12) + (e << 7) + ((e & 7) << 4);
#pragma unroll
                for (int m = 0; m < 8; ++m) {
                    float4 v = *(const float4*)((const char*)Tl + (boff ^ (m << 4)));
                    acc[4*m+0] += v.x; acc[4*m+1] += v.y;
                    acc[4*m+2] += v.z; acc[4*m+3] += v.w;
                }
            }
        } else {
            // generic tail (not hit for D=16)
            for (int i = t; i < dlen * 256; i += 256)
                cp16(Tg + c0 * 256 + i, Tl + i);
            __syncthreads();
            for (int d = 0; d < dlen; ++d) {
                int e = erow[c0 + d];
                int boff = (d << 12) + (e << 7) + ((e & 7) << 4);
#pragma unroll
                for (int m = 0; m < 8; ++m) {
                    float4 v = *(const float4*)((const char*)Tl + (boff ^ (m << 4)));
                    acc[4*m+0] += v.x; acc[4*m+1] += v.y;
                    acc[4*m+2] += v.z; acc[4*m+3] += v.w;
                }
            }
        }
    }

    if (!valid) return;

    // epilogue: interleave phi_spd (LDS gather) with phi_edge (pure reg) so
    // ds_read latency hides under the store stream.
    const float rs = 1.0f / (s_val ? (float)s_val : 1.0f);
    float* o0 = out + p0;                               // phi_spd
    float* o1 = out + (size_t)NH * npairs + p0;         // phi_edge
    const float* sA = Sl + s_val;
#pragma unroll
    for (int k = 0; k < 32; ++k) {
        o1[k * npairs] = acc[k] * rs;
        o0[k * npairs] = sA[k * ns];
    }
}

extern "C" void kernel_launch(void* const* d_in, const int* in_sizes, int n_in,
                              void* d_out, int out_size, void* d_ws, size_t ws_size,
                              hipStream_t stream) {
    // dict order: [0]=spatial_pos [1]=edge_input [2]=max_dist [3]=spd_table
    //             [4]=edge_table  [5]=edge_dis_weight
    const int* spatial = (const int*)d_in[0];
    const int* edge    = (const int*)d_in[1];
    const void* spd    = d_in[3];
    const void* etab   = d_in[4];
    const void* W      = d_in[5];

    long long npairs = in_sizes[0];
    long long etot   = in_sizes[1];
    int D = (int)(etot / (npairs > 0 ? npairs : 1));
    if (D < 1) D = 1;
    if (D > 64) D = 64;
    int spd_n  = in_sizes[3];
    int ns     = spd_n >> 5;          // spatial vocab (64 here)
    int totalT = D * 1024;

    float* T    = (float*)d_ws;        // D*1024 fp32, pre-swizzled
    float* spdT = T + totalT;          // spd_n fp32, transposed [h][s]

    prep<<<(totalT + spd_n + 255) / 256, 256, 0, stream>>>(
        etab, W, spd, T, spdT, totalT, spd_n);

    int nblk = (int)((npairs + 255) / 256);
    bond2d<<<nblk, 256, 0, stream>>>(spatial, edge, (const float4*)spdT,
                                     (const float4*)T, (float*)d_out,
                                     (int)npairs, D, ns);
}